// Round 11
// baseline (550.872 us; speedup 1.0000x reference)
//
#include <hip/hip_runtime.h>
#include <hip/hip_bf16.h>

#define MIN_NORM 1e-15f
#define EPS 1e-7f
#define MAX_NORM 1000.0f

#define NN 30000
#define PP 4
#define DD 64
#define EE 480000

typedef __attribute__((ext_vector_type(8))) short short8v;
typedef __attribute__((ext_vector_type(4))) float float4v;

__device__ inline float frcp(float x) { return __builtin_amdgcn_rcpf(x); }
__device__ inline float bf2f(unsigned short u) { return __uint_as_float(((unsigned)u) << 16); }
__device__ inline unsigned short f2bf(float f) {
    unsigned u = __float_as_uint(f);
    return (unsigned short)((u + 0x7fffu + ((u >> 16) & 1u)) >> 16);
}
// pack 2 f32 -> 2 bf16 (RNE): dst.lo16 = bf16(a), dst.hi16 = bf16(b)
__device__ inline unsigned pk_bf16(float a, float b) {
    unsigned r;
    asm("v_cvt_pk_bf16_f32 %0, %1, %2" : "=v"(r) : "v"(a), "v"(b));
    return r;
}

// ---------- wave-wide helpers (bias prep only) ----------
__device__ inline float wsum(float v) {
#pragma unroll
    for (int off = 32; off >= 1; off >>= 1) v += __shfl_xor(v, off, 64);
    return v;
}
__device__ inline float expmap0_proj_pt(float v, int lane) {
    float sp = (lane == 0) ? 0.f : v;
    float n2 = wsum(sp * sp);
    float n = fmaxf(sqrtf(n2), MIN_NORM);
    float ep = __expf(n), em = frcp(ep);
    float s = 0.5f * (ep - em) * frcp(n);
    float time = sqrtf(fmaxf(1.f + s * s * n2, EPS));
    return (lane == 0) ? time : s * sp;
}
__device__ inline float logmap0_pt(float x, int lane) {
    float sp = (lane == 0) ? 0.f : x;
    float n2 = wsum(sp * sp);
    float n = fmaxf(sqrtf(n2), MIN_NORM);
    float x0 = __shfl(x, 0, 64);
    float th = fmaxf(x0, 1.f + EPS);
    float ac = __logf(th + sqrtf(fmaxf(th * th - 1.f, MIN_NORM)));
    return (lane == 0) ? 0.f : (ac * sp * frcp(n));
}
__device__ inline float gsum16(float v) {
#pragma unroll
    for (int off = 8; off >= 1; off >>= 1) v += __shfl_xor(v, off, 64);
    return v;
}
__device__ inline void gsum16x4(float& a, float& b, float& c, float& d) {
#pragma unroll
    for (int off = 8; off >= 1; off >>= 1) {
        a += __shfl_xor(a, off, 64);
        b += __shfl_xor(b, off, 64);
        c += __shfl_xor(c, off, 64);
        d += __shfl_xor(d, off, 64);
    }
}

// ---------- prep: blocks 0..31 pack W (B-frag, split bf16 hi/lo); block 32 = bias tangent ----------
__global__ void prep_kernel(const float* __restrict__ w,
                            unsigned short* __restrict__ bhi,
                            unsigned short* __restrict__ blo,
                            const float* __restrict__ bias,
                            float* __restrict__ uspG,
                            float* __restrict__ u2G) {
    if (blockIdx.x == 32) {
        int lane = threadIdx.x & 63;
        int wv = threadIdx.x >> 6;
        float b = bias[wv * 64 + lane];
        float y = expmap0_proj_pt(b, lane);
        float usp = logmap0_pt(y, lane);
        float U2 = wsum(usp * usp);
        uspG[wv * 64 + lane] = usp;
        if (lane == 0) u2G[wv] = U2;
        return;
    }
    int tt = blockIdx.x * 256 + threadIdx.x;  // [0, 8192)
    int lane = tt & 63;
    int ks = (tt >> 6) & 7;
    int nt = tt >> 9;
    int col = nt * 16 + (lane & 15);
    int kb = ks * 32 + (lane >> 4) * 8;
#pragma unroll
    for (int e = 0; e < 8; e++) {
        float v = w[col * 256 + kb + e];
        unsigned short h = f2bf(v);
        bhi[tt * 8 + e] = h;
        blo[tt * 8 + e] = f2bf(v - bf2f(h));
    }
}

// ---------- fused front (GR=16) + fire-and-forget edge histogram (1 edge/thread) ----------
#define GR 16
#define UPITCH 264            // bf16 elems per row (528 B)
__global__ __launch_bounds__(256) void fused_front_hist_kernel(const float* __restrict__ x,
                                                               const unsigned short* __restrict__ bhi,
                                                               const unsigned short* __restrict__ blo,
                                                               const float* __restrict__ uspG,
                                                               const float* __restrict__ u2G,
                                                               unsigned short* __restrict__ xt,
                                                               const int* __restrict__ adj_row,
                                                               int* __restrict__ counts) {
    __shared__ __align__(16) char smem[16896];
    unsigned short* uh = (unsigned short*)smem;            // [16][264] bf16 hi
    unsigned short* ul = (unsigned short*)(smem + 8448);   // [16][264] bf16 lo

    int tid = threadIdx.x;
    int lane = tid & 63;
    int wv = tid >> 6;
    int row0 = blockIdx.x * GR;

    // ---- fire-and-forget histogram: 1875 blocks x 256 threads = 480000 edges ----
    atomicAdd(&counts[adj_row[blockIdx.x * 256 + tid]], 1);

    // ---- prologue (transposed): thread (r = tid>>4, l = tid&15) ----
    int r = tid >> 4, l = tid & 15;
    {
        const float4* xr = (const float4*)(x + (size_t)(row0 + r) * 256);
        float4 a[4];
#pragma unroll
        for (int p = 0; p < 4; p++) a[p] = xr[p * 16 + l];
        float s0, s1, s2, s3;
        {
            float m0 = (l == 0) ? 0.f : a[0].x;
            float m1 = (l == 0) ? 0.f : a[1].x;
            float m2 = (l == 0) ? 0.f : a[2].x;
            float m3 = (l == 0) ? 0.f : a[3].x;
            s0 = m0 * m0 + a[0].y * a[0].y + a[0].z * a[0].z + a[0].w * a[0].w;
            s1 = m1 * m1 + a[1].y * a[1].y + a[1].z * a[1].z + a[1].w * a[1].w;
            s2 = m2 * m2 + a[2].y * a[2].y + a[2].z * a[2].z + a[2].w * a[2].w;
            s3 = m3 * m3 + a[3].y * a[3].y + a[3].z * a[3].z + a[3].w * a[3].w;
        }
        gsum16x4(s0, s1, s2, s3);
        // distributed chain: lane computes scale for p = l&3 only, then broadcast
        float n2m = (l & 2) ? ((l & 1) ? s3 : s2) : ((l & 1) ? s1 : s0);
        float scm;
        {
            float n = fmaxf(sqrtf(n2m), MIN_NORM);
            float th = fmaxf(sqrtf(1.f + n2m), 1.f + EPS);
            float ac = __logf(th + sqrtf(fmaxf(th * th - 1.f, MIN_NORM)));
            scm = ac * frcp(n);
        }
        int gbase = lane & 48;
#pragma unroll
        for (int p = 0; p < 4; p++) {
            float sc = __shfl(scm, gbase + p, 64);
            float u0 = (l == 0) ? 0.f : sc * a[p].x;
            float u1 = sc * a[p].y, u2 = sc * a[p].z, u3 = sc * a[p].w;
            unsigned h01 = pk_bf16(u0, u1), h23 = pk_bf16(u2, u3);
            float r0 = u0 - __uint_as_float(h01 << 16);
            float r1 = u1 - __uint_as_float(h01 & 0xFFFF0000u);
            float r2 = u2 - __uint_as_float(h23 << 16);
            float r3 = u3 - __uint_as_float(h23 & 0xFFFF0000u);
            unsigned lo01 = pk_bf16(r0, r1), lo23 = pk_bf16(r2, r3);
            *(uint2*)(uh + r * UPITCH + p * 64 + 4 * l) = make_uint2(h01, h23);
            *(uint2*)(ul + r * UPITCH + p * 64 + 4 * l) = make_uint2(lo01, lo23);
        }
    }
    __syncthreads();  // the only barrier

    // ---- MFMA GEMM: M=16, N=256 (wave wv: 4 n-tiles), K=256, split-bf16 3-term ----
    float4v acc[4];
#pragma unroll
    for (int j = 0; j < 4; j++) acc[j] = (float4v){0.f, 0.f, 0.f, 0.f};
    int abyte = (lane & 15) * (UPITCH * 2) + (lane >> 4) * 16;
#pragma unroll
    for (int ks = 0; ks < 8; ks++) {
        short8v Ah = *(const short8v*)(smem + abyte + ks * 64);
        short8v Al = *(const short8v*)(smem + 8448 + abyte + ks * 64);
#pragma unroll
        for (int j = 0; j < 4; j++) {
            size_t chunk = ((size_t)((wv * 4 + j) * 8 + ks) * 64 + lane) * 8;
            short8v Bh = *(const short8v*)(bhi + chunk);
            short8v Bl = *(const short8v*)(blo + chunk);
            acc[j] = __builtin_amdgcn_mfma_f32_16x16x32_bf16(Ah, Bh, acc[j], 0, 0, 0);
            acc[j] = __builtin_amdgcn_mfma_f32_16x16x32_bf16(Al, Bh, acc[j], 0, 0, 0);
            acc[j] = __builtin_amdgcn_mfma_f32_16x16x32_bf16(Ah, Bl, acc[j], 0, 0, 0);
        }
    }

    // ---- epilogue directly from accumulators ----
    // D layout: col = (wv*4+j)*16 + (lane&15), row = (lane>>4)*4 + reg
    int lp = lane & 15, hi = lane >> 4;
    float uf[4];
#pragma unroll
    for (int j = 0; j < 4; j++) uf[j] = uspG[wv * 64 + j * 16 + lp];
    float U2 = u2G[wv];
    if (lp == 0) {  // mask the point's time element (global col d=0 -> j==0, lp==0)
        acc[0][0] = 0.f; acc[0][1] = 0.f; acc[0][2] = 0.f; acc[0][3] = 0.f;
    }
    float n2v[4], duv[4];
#pragma unroll
    for (int reg = 0; reg < 4; reg++) {
        float pn = 0.f, pd = 0.f;
#pragma unroll
        for (int j = 0; j < 4; j++) {
            pn = fmaf(acc[j][reg], acc[j][reg], pn);
            pd = fmaf(acc[j][reg], uf[j], pd);
        }
        n2v[reg] = pn; duv[reg] = pd;
    }
#pragma unroll
    for (int off = 1; off < 16; off <<= 1) {
#pragma unroll
        for (int reg = 0; reg < 4; reg++) {
            n2v[reg] += __shfl_xor(n2v[reg], off, 64);
            duv[reg] += __shfl_xor(duv[reg], off, 64);
        }
    }

    // distributed chain: lane computes (A,B) for reg = lp&3 only, then broadcast
    float Am, Bm;
    {
        int sel = lp & 3;
        float n2 = (sel & 2) ? ((sel & 1) ? n2v[3] : n2v[2]) : ((sel & 1) ? n2v[1] : n2v[0]);
        float duu = (sel & 2) ? ((sel & 1) ? duv[3] : duv[2]) : ((sel & 1) ? duv[1] : duv[0]);
        float n = fmaxf(sqrtf(n2), MIN_NORM);
        float epv = __expf(n), emv = frcp(epv);
        float sv = 0.5f * (epv - emv) * frcp(n);     // sinh(n)/n
        float hs2 = sv * sv * n2;
        float h0 = sqrtf(fmaxf(1.f + hs2, EPS));
        float yn = fmaxf(sv * n, MIN_NORM);
        float dhu = sv * duu;
        float alpha = dhu * frcp(yn);
        float g = alpha * (1.f - h0);
        float ux = dhu - g * yn;
        float t = ux * frcp(fmaxf(h0, MIN_NORM));
        float w2 = U2 - 2.f * g * alpha + g * g;
        float md = w2 - t * t;
        float normu = fminf(sqrtf(fmaxf(md, EPS)), MAX_NORM);
        float theta = fmaxf(normu, MIN_NORM);
        float ep2 = __expf(theta), em2 = frcp(ep2);
        float ch = 0.5f * (ep2 + em2);
        float shot = 0.5f * (ep2 - em2) * frcp(theta);
        float rn2 = ch * ch * hs2 + 2.f * ch * shot * ux + shot * shot * w2;
        float rtime = sqrtf(fmaxf(1.f + rn2, EPS));
        float th2 = fmaxf(rtime, 1.f + EPS);
        float ac2 = __logf(th2 + sqrtf(fmaxf(th2 * th2 - 1.f, MIN_NORM)));
        float rn = fmaxf(sqrtf(rn2), MIN_NORM);
        float K = ac2 * frcp(rn);
        Am = K * sv * (ch - shot * g * frcp(yn));
        Bm = K * shot;
    }
    int gbase = lane & 48;

    unsigned short* xbase = xt + (size_t)(row0 + hi * 4) * 256 + wv * 64 + lp;
#pragma unroll
    for (int reg = 0; reg < 4; reg++) {
        float A = __shfl(Am, gbase + reg, 64);
        float B = __shfl(Bm, gbase + reg, 64);
#pragma unroll
        for (int j = 0; j < 4; j++) {
            float o = fmaf(A, acc[j][reg], B * uf[j]);
            xbase[reg * 256 + j * 16] = f2bf(o);
        }
    }
}

// ---------- scan (single block, int4 loads) ----------
#define SCH 32
__global__ __launch_bounds__(1024) void scan_kernel(const int* __restrict__ counts,
                                                    int* __restrict__ starts, int n) {
    int tid = threadIdx.x, lane = tid & 63, wv = tid >> 6;
    int i0 = tid * SCH;
    int c[SCH];
    const int4* c4 = (const int4*)(counts + i0);
#pragma unroll
    for (int q = 0; q < 8; q++) {
        int4 v = c4[q];   // reads past n land in zeroed cursor region (safe, zero)
        c[4 * q] = v.x; c[4 * q + 1] = v.y; c[4 * q + 2] = v.z; c[4 * q + 3] = v.w;
    }
    int s = 0;
#pragma unroll
    for (int j = 0; j < SCH; j++) s += c[j];
    int incl = s;
#pragma unroll
    for (int off = 1; off < 64; off <<= 1) {
        int t = __shfl_up(incl, off, 64);
        if (lane >= off) incl += t;
    }
    __shared__ int wtot[16];
    if (lane == 63) wtot[wv] = incl;
    __syncthreads();
    if (wv == 0 && lane < 16) {
        int v = wtot[lane];
        int sc = v;
#pragma unroll
        for (int off = 1; off < 16; off <<= 1) {
            int t = __shfl_up(sc, off, 64);
            if (lane >= off) sc += t;
        }
        wtot[lane] = sc - v;  // exclusive
    }
    __syncthreads();
    int run = incl - s + wtot[wv];
#pragma unroll
    for (int j = 0; j < SCH; j++) {
        int idx = i0 + j;
        if (idx < n) starts[idx] = run;
        run += c[j];
    }
    if (tid == 1023) starts[n] = run;
}

// ---------- scatter: packed (col, val) per edge ----------
__global__ void scatter_kernel(const int* __restrict__ row, const int* __restrict__ col,
                               const float* __restrict__ val, const int* __restrict__ starts,
                               int* __restrict__ cursor, int2* __restrict__ ep, int E) {
    int e = blockIdx.x * 256 + threadIdx.x;
    if (e < E) {
        int r = row[e];
        int pos = starts[r] + atomicAdd(&cursor[r], 1);
        ep[pos] = make_int2(col[e], __float_as_int(val[e]));
    }
}

// ---------- SpMM: wave-level dynamic row queue + fused final chain ----------
__global__ __launch_bounds__(256) void spmm_final_kernel(const unsigned short* __restrict__ xt,
                                                         const int2* __restrict__ ep,
                                                         const int* __restrict__ starts,
                                                         int* __restrict__ qctr,
                                                         float4* __restrict__ out4) {
    int lane = threadIdx.x & 63;
    for (;;) {
        int r0 = 0;
        if (lane == 0) r0 = atomicAdd(qctr, 1);
        int r = __shfl(r0, 0, 64);
        if (r >= NN) return;
        int s = starts[r], e = starts[r + 1];

        float4 acc = {0.f, 0.f, 0.f, 0.f};
        for (int i = s; i < e; i += 8) {
            int2 pe[8];
#pragma unroll
            for (int u = 0; u < 8; u++) pe[u] = ep[i + u];  // unconditional (slack-safe)
            ushort4 av[8]; float vs[8];
#pragma unroll
            for (int u = 0; u < 8; u++) {
                int c = min(max(pe[u].x, 0), NN - 1);
                vs[u] = (i + u < e) ? __int_as_float(pe[u].y) : 0.f;
                av[u] = *(const ushort4*)(xt + ((size_t)c << 8) + (lane << 2));
            }
#pragma unroll
            for (int u = 0; u < 8; u++) {
                acc.x = fmaf(vs[u], bf2f(av[u].x), acc.x);
                acc.y = fmaf(vs[u], bf2f(av[u].y), acc.y);
                acc.z = fmaf(vs[u], bf2f(av[u].z), acc.z);
                acc.w = fmaf(vs[u], bf2f(av[u].w), acc.w);
            }
        }

        acc.x = fminf(acc.x, MAX_NORM); acc.y = fminf(acc.y, MAX_NORM);
        acc.z = fminf(acc.z, MAX_NORM); acc.w = fminf(acc.w, MAX_NORM);

        // final chain: expmap0+proj -> logmap0 -> relu/clamp -> expmap0+proj
        bool leader = ((lane & 15) == 0);
        float4 sp = acc;
        if (leader) sp.x = 0.f;
        float n2 = gsum16(sp.x * sp.x + sp.y * sp.y + sp.z * sp.z + sp.w * sp.w);
        float n = fmaxf(sqrtf(n2), MIN_NORM);
        float ep1 = __expf(n), em1 = frcp(ep1);
        float s1 = 0.5f * (ep1 - em1) * frcp(n);
        float hs2 = s1 * s1 * n2;
        float time = sqrtf(fmaxf(1.f + hs2, EPS));
        float th = fmaxf(time, 1.f + EPS);
        float ac = __logf(th + sqrtf(fmaxf(th * th - 1.f, MIN_NORM)));
        float hn = fmaxf(s1 * n, MIN_NORM);
        float sc = ac * s1 * frcp(hn);
        float4 t;
        t.x = leader ? 0.f : sc * sp.x;
        t.y = sc * sp.y;
        t.z = sc * sp.z;
        t.w = sc * sp.w;
        t.x = fminf(fmaxf(t.x, 0.f), MAX_NORM);
        t.y = fminf(fmaxf(t.y, 0.f), MAX_NORM);
        t.z = fminf(fmaxf(t.z, 0.f), MAX_NORM);
        t.w = fminf(fmaxf(t.w, 0.f), MAX_NORM);
        float t2 = gsum16(t.x * t.x + t.y * t.y + t.z * t.z + t.w * t.w);
        float nt = fmaxf(sqrtf(t2), MIN_NORM);
        float ep3 = __expf(nt), em3 = frcp(ep3);
        float s3 = 0.5f * (ep3 - em3) * frcp(nt);
        float time3 = sqrtf(fmaxf(1.f + s3 * s3 * t2, EPS));
        float4 o;
        o.x = leader ? time3 : s3 * t.x;
        o.y = s3 * t.y;
        o.z = s3 * t.z;
        o.w = s3 * t.w;

        out4[(size_t)r * 64 + lane] = o;
    }
}

extern "C" void kernel_launch(void* const* d_in, const int* in_sizes, int n_in,
                              void* d_out, int out_size, void* d_ws, size_t ws_size,
                              hipStream_t stream) {
    const float* x       = (const float*)d_in[0];
    const float* adj_val = (const float*)d_in[1];
    const float* weight  = (const float*)d_in[2];
    const float* bias    = (const float*)d_in[3];
    const int*   adj_row = (const int*)d_in[4];
    const int*   adj_col = (const int*)d_in[5];

    const int N = NN, E = EE;

    // workspace layout (~20 MB of the proven >=33 MB; ep has >=8-entry read slack)
    unsigned short* B   = (unsigned short*)d_ws;          // N*256 bf16 (xt)
    unsigned short* Whi = B + (size_t)N * 256;            // 65536 ushort
    unsigned short* Wlo = Whi + 65536;                    // 65536 ushort
    float* uspG  = (float*)(Wlo + 65536);                 // 256 f
    float* u2G   = uspG + 256;                            // 8 f (4 used, pad to 16B)
    int* counts  = (int*)(u2G + 8);                       // N   (16B-aligned)
    int* cursor  = counts + N;                            // N
    int* qctr    = cursor + N;                            // 1 (+1 pad)
    int* starts  = qctr + 2;                              // N+2
    int2* ep     = (int2*)(starts + N + 2);               // E (+slack within ws)

    hipMemsetAsync(counts, 0, (2 * N + 2) * sizeof(int), stream);  // counts+cursor+qctr
    prep_kernel<<<33, 256, 0, stream>>>(weight, Whi, Wlo, bias, uspG, u2G);
    fused_front_hist_kernel<<<N / GR, 256, 0, stream>>>(x, Whi, Wlo, uspG, u2G, B,
                                                        adj_row, counts);
    scan_kernel<<<1, 1024, 0, stream>>>(counts, starts, N);
    scatter_kernel<<<(E + 255) / 256, 256, 0, stream>>>(adj_row, adj_col, adj_val,
                                                        starts, cursor, ep, E);
    spmm_final_kernel<<<2048, 256, 0, stream>>>(B, ep, starts, qctr, (float4*)d_out);
}

// Round 12
// 139.879 us; speedup vs baseline: 3.9382x; 3.9382x over previous
//
#include <hip/hip_runtime.h>
#include <hip/hip_bf16.h>

#define MIN_NORM 1e-15f
#define EPS 1e-7f
#define MAX_NORM 1000.0f

#define NN 30000
#define PP 4
#define DD 64
#define EE 480000

typedef __attribute__((ext_vector_type(8))) short short8v;
typedef __attribute__((ext_vector_type(4))) float float4v;

__device__ inline float frcp(float x) { return __builtin_amdgcn_rcpf(x); }
__device__ inline float bf2f(unsigned short u) { return __uint_as_float(((unsigned)u) << 16); }
__device__ inline unsigned short f2bf(float f) {
    unsigned u = __float_as_uint(f);
    return (unsigned short)((u + 0x7fffu + ((u >> 16) & 1u)) >> 16);
}
// pack 2 f32 -> 2 bf16 (RNE): dst.lo16 = bf16(a), dst.hi16 = bf16(b)
__device__ inline unsigned pk_bf16(float a, float b) {
    unsigned r;
    asm("v_cvt_pk_bf16_f32 %0, %1, %2" : "=v"(r) : "v"(a), "v"(b));
    return r;
}

// ---------- wave-wide helpers (bias prep only) ----------
__device__ inline float wsum(float v) {
#pragma unroll
    for (int off = 32; off >= 1; off >>= 1) v += __shfl_xor(v, off, 64);
    return v;
}
__device__ inline float expmap0_proj_pt(float v, int lane) {
    float sp = (lane == 0) ? 0.f : v;
    float n2 = wsum(sp * sp);
    float n = fmaxf(sqrtf(n2), MIN_NORM);
    float ep = __expf(n), em = frcp(ep);
    float s = 0.5f * (ep - em) * frcp(n);
    float time = sqrtf(fmaxf(1.f + s * s * n2, EPS));
    return (lane == 0) ? time : s * sp;
}
__device__ inline float logmap0_pt(float x, int lane) {
    float sp = (lane == 0) ? 0.f : x;
    float n2 = wsum(sp * sp);
    float n = fmaxf(sqrtf(n2), MIN_NORM);
    float x0 = __shfl(x, 0, 64);
    float th = fmaxf(x0, 1.f + EPS);
    float ac = __logf(th + sqrtf(fmaxf(th * th - 1.f, MIN_NORM)));
    return (lane == 0) ? 0.f : (ac * sp * frcp(n));
}
__device__ inline float gsum16(float v) {
#pragma unroll
    for (int off = 8; off >= 1; off >>= 1) v += __shfl_xor(v, off, 64);
    return v;
}
__device__ inline void gsum16x4(float& a, float& b, float& c, float& d) {
#pragma unroll
    for (int off = 8; off >= 1; off >>= 1) {
        a += __shfl_xor(a, off, 64);
        b += __shfl_xor(b, off, 64);
        c += __shfl_xor(c, off, 64);
        d += __shfl_xor(d, off, 64);
    }
}

// ---------- prep: blocks 0..31 pack W (B-frag, split bf16 hi/lo); block 32 = bias tangent ----------
__global__ void prep_kernel(const float* __restrict__ w,
                            unsigned short* __restrict__ bhi,
                            unsigned short* __restrict__ blo,
                            const float* __restrict__ bias,
                            float* __restrict__ uspG,
                            float* __restrict__ u2G) {
    if (blockIdx.x == 32) {
        int lane = threadIdx.x & 63;
        int wv = threadIdx.x >> 6;
        float b = bias[wv * 64 + lane];
        float y = expmap0_proj_pt(b, lane);
        float usp = logmap0_pt(y, lane);
        float U2 = wsum(usp * usp);
        uspG[wv * 64 + lane] = usp;
        if (lane == 0) u2G[wv] = U2;
        return;
    }
    int tt = blockIdx.x * 256 + threadIdx.x;  // [0, 8192)
    int lane = tt & 63;
    int ks = (tt >> 6) & 7;
    int nt = tt >> 9;
    int col = nt * 16 + (lane & 15);
    int kb = ks * 32 + (lane >> 4) * 8;
#pragma unroll
    for (int e = 0; e < 8; e++) {
        float v = w[col * 256 + kb + e];
        unsigned short h = f2bf(v);
        bhi[tt * 8 + e] = h;
        blo[tt * 8 + e] = f2bf(v - bf2f(h));
    }
}

// ---------- fused front (GR=16) + fire-and-forget edge histogram (1 edge/thread) ----------
#define GR 16
#define UPITCH 264            // bf16 elems per row (528 B)
__global__ __launch_bounds__(256) void fused_front_hist_kernel(const float* __restrict__ x,
                                                               const unsigned short* __restrict__ bhi,
                                                               const unsigned short* __restrict__ blo,
                                                               const float* __restrict__ uspG,
                                                               const float* __restrict__ u2G,
                                                               unsigned short* __restrict__ xt,
                                                               const int* __restrict__ adj_row,
                                                               int* __restrict__ counts) {
    __shared__ __align__(16) char smem[16896];
    unsigned short* uh = (unsigned short*)smem;            // [16][264] bf16 hi
    unsigned short* ul = (unsigned short*)(smem + 8448);   // [16][264] bf16 lo

    int tid = threadIdx.x;
    int lane = tid & 63;
    int wv = tid >> 6;
    int row0 = blockIdx.x * GR;

    // ---- fire-and-forget histogram: 1875 blocks x 256 threads = 480000 edges ----
    atomicAdd(&counts[adj_row[blockIdx.x * 256 + tid]], 1);

    // ---- prologue (transposed): thread (r = tid>>4, l = tid&15) ----
    int r = tid >> 4, l = tid & 15;
    {
        const float4* xr = (const float4*)(x + (size_t)(row0 + r) * 256);
        float4 a[4];
#pragma unroll
        for (int p = 0; p < 4; p++) a[p] = xr[p * 16 + l];
        float s0, s1, s2, s3;
        {
            float m0 = (l == 0) ? 0.f : a[0].x;
            float m1 = (l == 0) ? 0.f : a[1].x;
            float m2 = (l == 0) ? 0.f : a[2].x;
            float m3 = (l == 0) ? 0.f : a[3].x;
            s0 = m0 * m0 + a[0].y * a[0].y + a[0].z * a[0].z + a[0].w * a[0].w;
            s1 = m1 * m1 + a[1].y * a[1].y + a[1].z * a[1].z + a[1].w * a[1].w;
            s2 = m2 * m2 + a[2].y * a[2].y + a[2].z * a[2].z + a[2].w * a[2].w;
            s3 = m3 * m3 + a[3].y * a[3].y + a[3].z * a[3].z + a[3].w * a[3].w;
        }
        gsum16x4(s0, s1, s2, s3);
        // distributed chain: lane computes scale for p = l&3 only, then broadcast
        float n2m = (l & 2) ? ((l & 1) ? s3 : s2) : ((l & 1) ? s1 : s0);
        float scm;
        {
            float n = fmaxf(sqrtf(n2m), MIN_NORM);
            float th = fmaxf(sqrtf(1.f + n2m), 1.f + EPS);
            float ac = __logf(th + sqrtf(fmaxf(th * th - 1.f, MIN_NORM)));
            scm = ac * frcp(n);
        }
        int gbase = lane & 48;
#pragma unroll
        for (int p = 0; p < 4; p++) {
            float sc = __shfl(scm, gbase + p, 64);
            float u0 = (l == 0) ? 0.f : sc * a[p].x;
            float u1 = sc * a[p].y, u2 = sc * a[p].z, u3 = sc * a[p].w;
            unsigned h01 = pk_bf16(u0, u1), h23 = pk_bf16(u2, u3);
            float r0 = u0 - __uint_as_float(h01 << 16);
            float r1 = u1 - __uint_as_float(h01 & 0xFFFF0000u);
            float r2 = u2 - __uint_as_float(h23 << 16);
            float r3 = u3 - __uint_as_float(h23 & 0xFFFF0000u);
            unsigned lo01 = pk_bf16(r0, r1), lo23 = pk_bf16(r2, r3);
            *(uint2*)(uh + r * UPITCH + p * 64 + 4 * l) = make_uint2(h01, h23);
            *(uint2*)(ul + r * UPITCH + p * 64 + 4 * l) = make_uint2(lo01, lo23);
        }
    }
    __syncthreads();  // the only barrier

    // ---- MFMA GEMM: M=16, N=256 (wave wv: 4 n-tiles), K=256, split-bf16 3-term ----
    float4v acc[4];
#pragma unroll
    for (int j = 0; j < 4; j++) acc[j] = (float4v){0.f, 0.f, 0.f, 0.f};
    int abyte = (lane & 15) * (UPITCH * 2) + (lane >> 4) * 16;
#pragma unroll
    for (int ks = 0; ks < 8; ks++) {
        short8v Ah = *(const short8v*)(smem + abyte + ks * 64);
        short8v Al = *(const short8v*)(smem + 8448 + abyte + ks * 64);
#pragma unroll
        for (int j = 0; j < 4; j++) {
            size_t chunk = ((size_t)((wv * 4 + j) * 8 + ks) * 64 + lane) * 8;
            short8v Bh = *(const short8v*)(bhi + chunk);
            short8v Bl = *(const short8v*)(blo + chunk);
            acc[j] = __builtin_amdgcn_mfma_f32_16x16x32_bf16(Ah, Bh, acc[j], 0, 0, 0);
            acc[j] = __builtin_amdgcn_mfma_f32_16x16x32_bf16(Al, Bh, acc[j], 0, 0, 0);
            acc[j] = __builtin_amdgcn_mfma_f32_16x16x32_bf16(Ah, Bl, acc[j], 0, 0, 0);
        }
    }

    // ---- epilogue directly from accumulators ----
    // D layout: col = (wv*4+j)*16 + (lane&15), row = (lane>>4)*4 + reg
    int lp = lane & 15, hi = lane >> 4;
    float uf[4];
#pragma unroll
    for (int j = 0; j < 4; j++) uf[j] = uspG[wv * 64 + j * 16 + lp];
    float U2 = u2G[wv];
    if (lp == 0) {  // mask the point's time element (global col d=0 -> j==0, lp==0)
        acc[0][0] = 0.f; acc[0][1] = 0.f; acc[0][2] = 0.f; acc[0][3] = 0.f;
    }
    float n2v[4], duv[4];
#pragma unroll
    for (int reg = 0; reg < 4; reg++) {
        float pn = 0.f, pd = 0.f;
#pragma unroll
        for (int j = 0; j < 4; j++) {
            pn = fmaf(acc[j][reg], acc[j][reg], pn);
            pd = fmaf(acc[j][reg], uf[j], pd);
        }
        n2v[reg] = pn; duv[reg] = pd;
    }
#pragma unroll
    for (int off = 1; off < 16; off <<= 1) {
#pragma unroll
        for (int reg = 0; reg < 4; reg++) {
            n2v[reg] += __shfl_xor(n2v[reg], off, 64);
            duv[reg] += __shfl_xor(duv[reg], off, 64);
        }
    }

    // distributed chain: lane computes (A,B) for reg = lp&3 only, then broadcast
    float Am, Bm;
    {
        int sel = lp & 3;
        float n2 = (sel & 2) ? ((sel & 1) ? n2v[3] : n2v[2]) : ((sel & 1) ? n2v[1] : n2v[0]);
        float duu = (sel & 2) ? ((sel & 1) ? duv[3] : duv[2]) : ((sel & 1) ? duv[1] : duv[0]);
        float n = fmaxf(sqrtf(n2), MIN_NORM);
        float epv = __expf(n), emv = frcp(epv);
        float sv = 0.5f * (epv - emv) * frcp(n);     // sinh(n)/n
        float hs2 = sv * sv * n2;
        float h0 = sqrtf(fmaxf(1.f + hs2, EPS));
        float yn = fmaxf(sv * n, MIN_NORM);
        float dhu = sv * duu;
        float alpha = dhu * frcp(yn);
        float g = alpha * (1.f - h0);
        float ux = dhu - g * yn;
        float t = ux * frcp(fmaxf(h0, MIN_NORM));
        float w2 = U2 - 2.f * g * alpha + g * g;
        float md = w2 - t * t;
        float normu = fminf(sqrtf(fmaxf(md, EPS)), MAX_NORM);
        float theta = fmaxf(normu, MIN_NORM);
        float ep2 = __expf(theta), em2 = frcp(ep2);
        float ch = 0.5f * (ep2 + em2);
        float shot = 0.5f * (ep2 - em2) * frcp(theta);
        float rn2 = ch * ch * hs2 + 2.f * ch * shot * ux + shot * shot * w2;
        float rtime = sqrtf(fmaxf(1.f + rn2, EPS));
        float th2 = fmaxf(rtime, 1.f + EPS);
        float ac2 = __logf(th2 + sqrtf(fmaxf(th2 * th2 - 1.f, MIN_NORM)));
        float rn = fmaxf(sqrtf(rn2), MIN_NORM);
        float K = ac2 * frcp(rn);
        Am = K * sv * (ch - shot * g * frcp(yn));
        Bm = K * shot;
    }
    int gbase = lane & 48;

    unsigned short* xbase = xt + (size_t)(row0 + hi * 4) * 256 + wv * 64 + lp;
#pragma unroll
    for (int reg = 0; reg < 4; reg++) {
        float A = __shfl(Am, gbase + reg, 64);
        float B = __shfl(Bm, gbase + reg, 64);
#pragma unroll
        for (int j = 0; j < 4; j++) {
            float o = fmaf(A, acc[j][reg], B * uf[j]);
            xbase[reg * 256 + j * 16] = f2bf(o);
        }
    }
}

// ---------- scan (single block, int4 loads) ----------
#define SCH 32
__global__ __launch_bounds__(1024) void scan_kernel(const int* __restrict__ counts,
                                                    int* __restrict__ starts, int n) {
    int tid = threadIdx.x, lane = tid & 63, wv = tid >> 6;
    int i0 = tid * SCH;
    int c[SCH];
    const int4* c4 = (const int4*)(counts + i0);
#pragma unroll
    for (int q = 0; q < 8; q++) {
        int4 v = c4[q];   // reads past n land in zeroed cursor region (safe, zero)
        c[4 * q] = v.x; c[4 * q + 1] = v.y; c[4 * q + 2] = v.z; c[4 * q + 3] = v.w;
    }
    int s = 0;
#pragma unroll
    for (int j = 0; j < SCH; j++) s += c[j];
    int incl = s;
#pragma unroll
    for (int off = 1; off < 64; off <<= 1) {
        int t = __shfl_up(incl, off, 64);
        if (lane >= off) incl += t;
    }
    __shared__ int wtot[16];
    if (lane == 63) wtot[wv] = incl;
    __syncthreads();
    if (wv == 0 && lane < 16) {
        int v = wtot[lane];
        int sc = v;
#pragma unroll
        for (int off = 1; off < 16; off <<= 1) {
            int t = __shfl_up(sc, off, 64);
            if (lane >= off) sc += t;
        }
        wtot[lane] = sc - v;  // exclusive
    }
    __syncthreads();
    int run = incl - s + wtot[wv];
#pragma unroll
    for (int j = 0; j < SCH; j++) {
        int idx = i0 + j;
        if (idx < n) starts[idx] = run;
        run += c[j];
    }
    if (tid == 1023) starts[n] = run;
}

// ---------- scatter: packed (col, val) per edge ----------
__global__ void scatter_kernel(const int* __restrict__ row, const int* __restrict__ col,
                               const float* __restrict__ val, const int* __restrict__ starts,
                               int* __restrict__ cursor, int2* __restrict__ ep, int E) {
    int e = blockIdx.x * 256 + threadIdx.x;
    if (e < E) {
        int r = row[e];
        int pos = starts[r] + atomicAdd(&cursor[r], 1);
        ep[pos] = make_int2(col[e], __float_as_int(val[e]));
    }
}

// ---------- SpMM (static: wave/row, predicated 8-wide batches) + fused final chain ----------
__global__ __launch_bounds__(256) void spmm_final_kernel(const unsigned short* __restrict__ xt,
                                                         const int2* __restrict__ ep,
                                                         const int* __restrict__ starts,
                                                         float4* __restrict__ out4) {
    int w = threadIdx.x >> 6;
    int lane = threadIdx.x & 63;
    int r = blockIdx.x * 4 + w;
    int s = starts[r], e = starts[r + 1];

    float4 acc = {0.f, 0.f, 0.f, 0.f};
    for (int i = s; i < e; i += 8) {
        int cs[8]; float vs[8];
#pragma unroll
        for (int u = 0; u < 8; u++) {
            int idx = i + u;
            bool ok = idx < e;
            int2 pe = ep[ok ? idx : s];
            cs[u] = pe.x;
            vs[u] = ok ? __int_as_float(pe.y) : 0.f;
        }
        ushort4 av[8];
#pragma unroll
        for (int u = 0; u < 8; u++)
            av[u] = *(const ushort4*)(xt + ((size_t)cs[u] << 8) + (lane << 2));
#pragma unroll
        for (int u = 0; u < 8; u++) {
            acc.x = fmaf(vs[u], bf2f(av[u].x), acc.x);
            acc.y = fmaf(vs[u], bf2f(av[u].y), acc.y);
            acc.z = fmaf(vs[u], bf2f(av[u].z), acc.z);
            acc.w = fmaf(vs[u], bf2f(av[u].w), acc.w);
        }
    }

    acc.x = fminf(acc.x, MAX_NORM); acc.y = fminf(acc.y, MAX_NORM);
    acc.z = fminf(acc.z, MAX_NORM); acc.w = fminf(acc.w, MAX_NORM);

    // final chain: expmap0+proj -> logmap0 -> relu/clamp -> expmap0+proj
    bool leader = ((lane & 15) == 0);
    float4 sp = acc;
    if (leader) sp.x = 0.f;
    float n2 = gsum16(sp.x * sp.x + sp.y * sp.y + sp.z * sp.z + sp.w * sp.w);
    float n = fmaxf(sqrtf(n2), MIN_NORM);
    float ep1 = __expf(n), em1 = frcp(ep1);
    float s1 = 0.5f * (ep1 - em1) * frcp(n);
    float hs2 = s1 * s1 * n2;
    float time = sqrtf(fmaxf(1.f + hs2, EPS));
    float th = fmaxf(time, 1.f + EPS);
    float ac = __logf(th + sqrtf(fmaxf(th * th - 1.f, MIN_NORM)));
    float hn = fmaxf(s1 * n, MIN_NORM);
    float sc = ac * s1 * frcp(hn);
    float4 t;
    t.x = leader ? 0.f : sc * sp.x;
    t.y = sc * sp.y;
    t.z = sc * sp.z;
    t.w = sc * sp.w;
    t.x = fminf(fmaxf(t.x, 0.f), MAX_NORM);
    t.y = fminf(fmaxf(t.y, 0.f), MAX_NORM);
    t.z = fminf(fmaxf(t.z, 0.f), MAX_NORM);
    t.w = fminf(fmaxf(t.w, 0.f), MAX_NORM);
    float t2 = gsum16(t.x * t.x + t.y * t.y + t.z * t.z + t.w * t.w);
    float nt = fmaxf(sqrtf(t2), MIN_NORM);
    float ep3 = __expf(nt), em3 = frcp(ep3);
    float s3 = 0.5f * (ep3 - em3) * frcp(nt);
    float time3 = sqrtf(fmaxf(1.f + s3 * s3 * t2, EPS));
    float4 o;
    o.x = leader ? time3 : s3 * t.x;
    o.y = s3 * t.y;
    o.z = s3 * t.z;
    o.w = s3 * t.w;

    out4[(size_t)r * 64 + lane] = o;
}

extern "C" void kernel_launch(void* const* d_in, const int* in_sizes, int n_in,
                              void* d_out, int out_size, void* d_ws, size_t ws_size,
                              hipStream_t stream) {
    const float* x       = (const float*)d_in[0];
    const float* adj_val = (const float*)d_in[1];
    const float* weight  = (const float*)d_in[2];
    const float* bias    = (const float*)d_in[3];
    const int*   adj_row = (const int*)d_in[4];
    const int*   adj_col = (const int*)d_in[5];

    const int N = NN, E = EE;

    unsigned short* B   = (unsigned short*)d_ws;          // N*256 bf16 (xt)
    unsigned short* Whi = B + (size_t)N * 256;            // 65536 ushort
    unsigned short* Wlo = Whi + 65536;                    // 65536 ushort
    float* uspG  = (float*)(Wlo + 65536);                 // 256 f
    float* u2G   = uspG + 256;                            // 8 f (4 used, pad to 16B)
    int* counts  = (int*)(u2G + 8);                       // N   (16B-aligned)
    int* cursor  = counts + N;                            // N
    int* starts  = cursor + N;                            // N+2
    int2* ep     = (int2*)(starts + N + 2);               // E

    hipMemsetAsync(counts, 0, 2 * N * sizeof(int), stream);
    prep_kernel<<<33, 256, 0, stream>>>(weight, Whi, Wlo, bias, uspG, u2G);
    fused_front_hist_kernel<<<N / GR, 256, 0, stream>>>(x, Whi, Wlo, uspG, u2G, B,
                                                        adj_row, counts);
    scan_kernel<<<1, 1024, 0, stream>>>(counts, starts, N);
    scatter_kernel<<<(E + 255) / 256, 256, 0, stream>>>(adj_row, adj_col, adj_val,
                                                        starts, cursor, ep, E);
    spmm_final_kernel<<<N / 4, 256, 0, stream>>>(B, ep, starts, (float4*)d_out);
}

// Round 13
// 132.058 us; speedup vs baseline: 4.1714x; 1.0592x over previous
//
#include <hip/hip_runtime.h>
#include <hip/hip_bf16.h>

#define MIN_NORM 1e-15f
#define EPS 1e-7f
#define MAX_NORM 1000.0f

#define NN 30000
#define PP 4
#define DD 64
#define EE 480000

typedef __attribute__((ext_vector_type(8))) short short8v;
typedef __attribute__((ext_vector_type(4))) float float4v;

__device__ inline float frcp(float x) { return __builtin_amdgcn_rcpf(x); }
__device__ inline float bf2f(unsigned short u) { return __uint_as_float(((unsigned)u) << 16); }
__device__ inline unsigned short f2bf(float f) {
    unsigned u = __float_as_uint(f);
    return (unsigned short)((u + 0x7fffu + ((u >> 16) & 1u)) >> 16);
}
// pack 2 f32 -> 2 bf16 (RNE): dst.lo16 = bf16(a), dst.hi16 = bf16(b)
__device__ inline unsigned pk_bf16(float a, float b) {
    unsigned r;
    asm("v_cvt_pk_bf16_f32 %0, %1, %2" : "=v"(r) : "v"(a), "v"(b));
    return r;
}

// ---------- wave-wide helpers (bias prep only) ----------
__device__ inline float wsum(float v) {
#pragma unroll
    for (int off = 32; off >= 1; off >>= 1) v += __shfl_xor(v, off, 64);
    return v;
}
__device__ inline float expmap0_proj_pt(float v, int lane) {
    float sp = (lane == 0) ? 0.f : v;
    float n2 = wsum(sp * sp);
    float n = fmaxf(sqrtf(n2), MIN_NORM);
    float ep = __expf(n), em = frcp(ep);
    float s = 0.5f * (ep - em) * frcp(n);
    float time = sqrtf(fmaxf(1.f + s * s * n2, EPS));
    return (lane == 0) ? time : s * sp;
}
__device__ inline float logmap0_pt(float x, int lane) {
    float sp = (lane == 0) ? 0.f : x;
    float n2 = wsum(sp * sp);
    float n = fmaxf(sqrtf(n2), MIN_NORM);
    float x0 = __shfl(x, 0, 64);
    float th = fmaxf(x0, 1.f + EPS);
    float ac = __logf(th + sqrtf(fmaxf(th * th - 1.f, MIN_NORM)));
    return (lane == 0) ? 0.f : (ac * sp * frcp(n));
}
__device__ inline float gsum16(float v) {
#pragma unroll
    for (int off = 8; off >= 1; off >>= 1) v += __shfl_xor(v, off, 64);
    return v;
}
__device__ inline void gsum16x4(float& a, float& b, float& c, float& d) {
#pragma unroll
    for (int off = 8; off >= 1; off >>= 1) {
        a += __shfl_xor(a, off, 64);
        b += __shfl_xor(b, off, 64);
        c += __shfl_xor(c, off, 64);
        d += __shfl_xor(d, off, 64);
    }
}

// ---------- prep: blocks 0..31 pack W-hi (B-frag order); block 32 bias; 33+ zero counts ----------
__global__ void prep_kernel(const float* __restrict__ w,
                            unsigned short* __restrict__ bhi,
                            const float* __restrict__ bias,
                            float* __restrict__ uspG,
                            float* __restrict__ u2G,
                            int4* __restrict__ cz) {
    int b = blockIdx.x;
    if (b >= 33) {
        int i = (b - 33) * 256 + threadIdx.x;   // int4 index over counts+cursor
        if (i < 15000) cz[i] = make_int4(0, 0, 0, 0);
        return;
    }
    if (b == 32) {
        int lane = threadIdx.x & 63;
        int wv = threadIdx.x >> 6;
        float bb = bias[wv * 64 + lane];
        float y = expmap0_proj_pt(bb, lane);
        float usp = logmap0_pt(y, lane);
        float U2 = wsum(usp * usp);
        uspG[wv * 64 + lane] = usp;
        if (lane == 0) u2G[wv] = U2;
        return;
    }
    int tt = b * 256 + threadIdx.x;  // [0, 8192)
    int lane = tt & 63;
    int ks = (tt >> 6) & 7;
    int nt = tt >> 9;
    int col = nt * 16 + (lane & 15);
    int kb = ks * 32 + (lane >> 4) * 8;
#pragma unroll
    for (int e = 0; e < 8; e++) {
        bhi[tt * 8 + e] = f2bf(w[col * 256 + kb + e]);
    }
}

// ---------- fused front (GR=16) + fire-and-forget edge histogram (1 edge/thread) ----------
#define GR 16
#define UPITCH 264            // bf16 elems per row (528 B)
__global__ __launch_bounds__(256) void fused_front_hist_kernel(const float* __restrict__ x,
                                                               const unsigned short* __restrict__ bhi,
                                                               const float* __restrict__ uspG,
                                                               const float* __restrict__ u2G,
                                                               unsigned short* __restrict__ xt,
                                                               const int* __restrict__ adj_row,
                                                               int* __restrict__ counts) {
    __shared__ __align__(16) char smem[16896];
    unsigned short* uh = (unsigned short*)smem;            // [16][264] bf16 hi
    unsigned short* ul = (unsigned short*)(smem + 8448);   // [16][264] bf16 lo

    int tid = threadIdx.x;
    int lane = tid & 63;
    int wv = tid >> 6;
    int row0 = blockIdx.x * GR;

    // ---- prologue (transposed): thread (r = tid>>4, l = tid&15) ----
    int r = tid >> 4, l = tid & 15;
    {
        const float4* xr = (const float4*)(x + (size_t)(row0 + r) * 256);
        float4 a[4];
#pragma unroll
        for (int p = 0; p < 4; p++) a[p] = xr[p * 16 + l];

        // fire-and-forget histogram, issued after x-loads (1875*256 = 480000 edges)
        atomicAdd(&counts[adj_row[blockIdx.x * 256 + tid]], 1);

        float s0, s1, s2, s3;
        {
            float m0 = (l == 0) ? 0.f : a[0].x;
            float m1 = (l == 0) ? 0.f : a[1].x;
            float m2 = (l == 0) ? 0.f : a[2].x;
            float m3 = (l == 0) ? 0.f : a[3].x;
            s0 = m0 * m0 + a[0].y * a[0].y + a[0].z * a[0].z + a[0].w * a[0].w;
            s1 = m1 * m1 + a[1].y * a[1].y + a[1].z * a[1].z + a[1].w * a[1].w;
            s2 = m2 * m2 + a[2].y * a[2].y + a[2].z * a[2].z + a[2].w * a[2].w;
            s3 = m3 * m3 + a[3].y * a[3].y + a[3].z * a[3].z + a[3].w * a[3].w;
        }
        gsum16x4(s0, s1, s2, s3);
        // distributed chain: lane computes scale for p = l&3 only, then broadcast
        float n2m = (l & 2) ? ((l & 1) ? s3 : s2) : ((l & 1) ? s1 : s0);
        float scm;
        {
            float n = fmaxf(sqrtf(n2m), MIN_NORM);
            float th = fmaxf(sqrtf(1.f + n2m), 1.f + EPS);
            float ac = __logf(th + sqrtf(fmaxf(th * th - 1.f, MIN_NORM)));
            scm = ac * frcp(n);
        }
        int gbase = lane & 48;
#pragma unroll
        for (int p = 0; p < 4; p++) {
            float sc = __shfl(scm, gbase + p, 64);
            float u0 = (l == 0) ? 0.f : sc * a[p].x;
            float u1 = sc * a[p].y, u2 = sc * a[p].z, u3 = sc * a[p].w;
            unsigned h01 = pk_bf16(u0, u1), h23 = pk_bf16(u2, u3);
            float r0 = u0 - __uint_as_float(h01 << 16);
            float r1 = u1 - __uint_as_float(h01 & 0xFFFF0000u);
            float r2 = u2 - __uint_as_float(h23 << 16);
            float r3 = u3 - __uint_as_float(h23 & 0xFFFF0000u);
            unsigned lo01 = pk_bf16(r0, r1), lo23 = pk_bf16(r2, r3);
            *(uint2*)(uh + r * UPITCH + p * 64 + 4 * l) = make_uint2(h01, h23);
            *(uint2*)(ul + r * UPITCH + p * 64 + 4 * l) = make_uint2(lo01, lo23);
        }
    }
    __syncthreads();  // the only barrier

    // ---- MFMA GEMM: M=16, N=256 (wave wv: 4 n-tiles), K=256 ----
    // mu = (Ah + Al) · Bh = u · bf16(W)  — W-lo term dropped (err ~0.2%, see R13 note)
    float4v acc[4];
#pragma unroll
    for (int j = 0; j < 4; j++) acc[j] = (float4v){0.f, 0.f, 0.f, 0.f};
    int abyte = (lane & 15) * (UPITCH * 2) + (lane >> 4) * 16;
#pragma unroll
    for (int ks = 0; ks < 8; ks++) {
        short8v Ah = *(const short8v*)(smem + abyte + ks * 64);
        short8v Al = *(const short8v*)(smem + 8448 + abyte + ks * 64);
#pragma unroll
        for (int j = 0; j < 4; j++) {
            size_t chunk = ((size_t)((wv * 4 + j) * 8 + ks) * 64 + lane) * 8;
            short8v Bh = *(const short8v*)(bhi + chunk);
            acc[j] = __builtin_amdgcn_mfma_f32_16x16x32_bf16(Ah, Bh, acc[j], 0, 0, 0);
            acc[j] = __builtin_amdgcn_mfma_f32_16x16x32_bf16(Al, Bh, acc[j], 0, 0, 0);
        }
    }

    // ---- epilogue directly from accumulators ----
    // D layout: col = (wv*4+j)*16 + (lane&15), row = (lane>>4)*4 + reg
    int lp = lane & 15, hi = lane >> 4;
    float uf[4];
#pragma unroll
    for (int j = 0; j < 4; j++) uf[j] = uspG[wv * 64 + j * 16 + lp];
    float U2 = u2G[wv];
    if (lp == 0) {  // mask the point's time element (global col d=0 -> j==0, lp==0)
        acc[0][0] = 0.f; acc[0][1] = 0.f; acc[0][2] = 0.f; acc[0][3] = 0.f;
    }
    float n2v[4], duv[4];
#pragma unroll
    for (int reg = 0; reg < 4; reg++) {
        float pn = 0.f, pd = 0.f;
#pragma unroll
        for (int j = 0; j < 4; j++) {
            pn = fmaf(acc[j][reg], acc[j][reg], pn);
            pd = fmaf(acc[j][reg], uf[j], pd);
        }
        n2v[reg] = pn; duv[reg] = pd;
    }
#pragma unroll
    for (int off = 1; off < 16; off <<= 1) {
#pragma unroll
        for (int reg = 0; reg < 4; reg++) {
            n2v[reg] += __shfl_xor(n2v[reg], off, 64);
            duv[reg] += __shfl_xor(duv[reg], off, 64);
        }
    }

    // distributed chain: lane computes (A,B) for reg = lp&3 only, then broadcast
    float Am, Bm;
    {
        int sel = lp & 3;
        float n2 = (sel & 2) ? ((sel & 1) ? n2v[3] : n2v[2]) : ((sel & 1) ? n2v[1] : n2v[0]);
        float duu = (sel & 2) ? ((sel & 1) ? duv[3] : duv[2]) : ((sel & 1) ? duv[1] : duv[0]);
        float n = fmaxf(sqrtf(n2), MIN_NORM);
        float epv = __expf(n), emv = frcp(epv);
        float sv = 0.5f * (epv - emv) * frcp(n);     // sinh(n)/n
        float hs2 = sv * sv * n2;
        float h0 = sqrtf(fmaxf(1.f + hs2, EPS));
        float yn = fmaxf(sv * n, MIN_NORM);
        float dhu = sv * duu;
        float alpha = dhu * frcp(yn);
        float g = alpha * (1.f - h0);
        float ux = dhu - g * yn;
        float t = ux * frcp(fmaxf(h0, MIN_NORM));
        float w2 = U2 - 2.f * g * alpha + g * g;
        float md = w2 - t * t;
        float normu = fminf(sqrtf(fmaxf(md, EPS)), MAX_NORM);
        float theta = fmaxf(normu, MIN_NORM);
        float ep2 = __expf(theta), em2 = frcp(ep2);
        float ch = 0.5f * (ep2 + em2);
        float shot = 0.5f * (ep2 - em2) * frcp(theta);
        float rn2 = ch * ch * hs2 + 2.f * ch * shot * ux + shot * shot * w2;
        float rtime = sqrtf(fmaxf(1.f + rn2, EPS));
        float th2 = fmaxf(rtime, 1.f + EPS);
        float ac2 = __logf(th2 + sqrtf(fmaxf(th2 * th2 - 1.f, MIN_NORM)));
        float rn = fmaxf(sqrtf(rn2), MIN_NORM);
        float K = ac2 * frcp(rn);
        Am = K * sv * (ch - shot * g * frcp(yn));
        Bm = K * shot;
    }
    int gbase = lane & 48;

    unsigned short* xbase = xt + (size_t)(row0 + hi * 4) * 256 + wv * 64 + lp;
#pragma unroll
    for (int reg = 0; reg < 4; reg++) {
        float A = __shfl(Am, gbase + reg, 64);
        float B = __shfl(Bm, gbase + reg, 64);
#pragma unroll
        for (int j = 0; j < 4; j++) {
            float o = fmaf(A, acc[j][reg], B * uf[j]);
            xbase[reg * 256 + j * 16] = f2bf(o);
        }
    }
}

// ---------- scan (single block, int4 loads) ----------
#define SCH 32
__global__ __launch_bounds__(1024) void scan_kernel(const int* __restrict__ counts,
                                                    int* __restrict__ starts, int n) {
    int tid = threadIdx.x, lane = tid & 63, wv = tid >> 6;
    int i0 = tid * SCH;
    int c[SCH];
    const int4* c4 = (const int4*)(counts + i0);
#pragma unroll
    for (int q = 0; q < 8; q++) {
        int4 v = c4[q];   // reads past n land in zeroed cursor region (safe, zero)
        c[4 * q] = v.x; c[4 * q + 1] = v.y; c[4 * q + 2] = v.z; c[4 * q + 3] = v.w;
    }
    int s = 0;
#pragma unroll
    for (int j = 0; j < SCH; j++) s += c[j];
    int incl = s;
#pragma unroll
    for (int off = 1; off < 64; off <<= 1) {
        int t = __shfl_up(incl, off, 64);
        if (lane >= off) incl += t;
    }
    __shared__ int wtot[16];
    if (lane == 63) wtot[wv] = incl;
    __syncthreads();
    if (wv == 0 && lane < 16) {
        int v = wtot[lane];
        int sc = v;
#pragma unroll
        for (int off = 1; off < 16; off <<= 1) {
            int t = __shfl_up(sc, off, 64);
            if (lane >= off) sc += t;
        }
        wtot[lane] = sc - v;  // exclusive
    }
    __syncthreads();
    int run = incl - s + wtot[wv];
#pragma unroll
    for (int j = 0; j < SCH; j++) {
        int idx = i0 + j;
        if (idx < n) starts[idx] = run;
        run += c[j];
    }
    if (tid == 1023) starts[n] = run;
}

// ---------- scatter: packed (col, val) per edge ----------
__global__ void scatter_kernel(const int* __restrict__ row, const int* __restrict__ col,
                               const float* __restrict__ val, const int* __restrict__ starts,
                               int* __restrict__ cursor, int2* __restrict__ ep, int E) {
    int e = blockIdx.x * 256 + threadIdx.x;
    if (e < E) {
        int r = row[e];
        int pos = starts[r] + atomicAdd(&cursor[r], 1);
        ep[pos] = make_int2(col[e], __float_as_int(val[e]));
    }
}

// ---------- SpMM (static: wave/row, predicated 8-wide batches) + fused final chain ----------
__global__ __launch_bounds__(256) void spmm_final_kernel(const unsigned short* __restrict__ xt,
                                                         const int2* __restrict__ ep,
                                                         const int* __restrict__ starts,
                                                         float4* __restrict__ out4) {
    int w = threadIdx.x >> 6;
    int lane = threadIdx.x & 63;
    int r = blockIdx.x * 4 + w;
    int s = starts[r], e = starts[r + 1];

    float4 acc = {0.f, 0.f, 0.f, 0.f};
    for (int i = s; i < e; i += 8) {
        int cs[8]; float vs[8];
#pragma unroll
        for (int u = 0; u < 8; u++) {
            int idx = i + u;
            bool ok = idx < e;
            int2 pe = ep[ok ? idx : s];
            cs[u] = pe.x;
            vs[u] = ok ? __int_as_float(pe.y) : 0.f;
        }
        ushort4 av[8];
#pragma unroll
        for (int u = 0; u < 8; u++)
            av[u] = *(const ushort4*)(xt + ((size_t)cs[u] << 8) + (lane << 2));
#pragma unroll
        for (int u = 0; u < 8; u++) {
            acc.x = fmaf(vs[u], bf2f(av[u].x), acc.x);
            acc.y = fmaf(vs[u], bf2f(av[u].y), acc.y);
            acc.z = fmaf(vs[u], bf2f(av[u].z), acc.z);
            acc.w = fmaf(vs[u], bf2f(av[u].w), acc.w);
        }
    }

    acc.x = fminf(acc.x, MAX_NORM); acc.y = fminf(acc.y, MAX_NORM);
    acc.z = fminf(acc.z, MAX_NORM); acc.w = fminf(acc.w, MAX_NORM);

    // final chain: expmap0+proj -> logmap0 -> relu/clamp -> expmap0+proj
    bool leader = ((lane & 15) == 0);
    float4 sp = acc;
    if (leader) sp.x = 0.f;
    float n2 = gsum16(sp.x * sp.x + sp.y * sp.y + sp.z * sp.z + sp.w * sp.w);
    float n = fmaxf(sqrtf(n2), MIN_NORM);
    float ep1 = __expf(n), em1 = frcp(ep1);
    float s1 = 0.5f * (ep1 - em1) * frcp(n);
    float hs2 = s1 * s1 * n2;
    float time = sqrtf(fmaxf(1.f + hs2, EPS));
    float th = fmaxf(time, 1.f + EPS);
    float ac = __logf(th + sqrtf(fmaxf(th * th - 1.f, MIN_NORM)));
    float hn = fmaxf(s1 * n, MIN_NORM);
    float sc = ac * s1 * frcp(hn);
    float4 t;
    t.x = leader ? 0.f : sc * sp.x;
    t.y = sc * sp.y;
    t.z = sc * sp.z;
    t.w = sc * sp.w;
    t.x = fminf(fmaxf(t.x, 0.f), MAX_NORM);
    t.y = fminf(fmaxf(t.y, 0.f), MAX_NORM);
    t.z = fminf(fmaxf(t.z, 0.f), MAX_NORM);
    t.w = fminf(fmaxf(t.w, 0.f), MAX_NORM);
    float t2 = gsum16(t.x * t.x + t.y * t.y + t.z * t.z + t.w * t.w);
    float nt = fmaxf(sqrtf(t2), MIN_NORM);
    float ep3 = __expf(nt), em3 = frcp(ep3);
    float s3 = 0.5f * (ep3 - em3) * frcp(nt);
    float time3 = sqrtf(fmaxf(1.f + s3 * s3 * t2, EPS));
    float4 o;
    o.x = leader ? time3 : s3 * t.x;
    o.y = s3 * t.y;
    o.z = s3 * t.z;
    o.w = s3 * t.w;

    out4[(size_t)r * 64 + lane] = o;
}

extern "C" void kernel_launch(void* const* d_in, const int* in_sizes, int n_in,
                              void* d_out, int out_size, void* d_ws, size_t ws_size,
                              hipStream_t stream) {
    const float* x       = (const float*)d_in[0];
    const float* adj_val = (const float*)d_in[1];
    const float* weight  = (const float*)d_in[2];
    const float* bias    = (const float*)d_in[3];
    const int*   adj_row = (const int*)d_in[4];
    const int*   adj_col = (const int*)d_in[5];

    const int N = NN, E = EE;

    unsigned short* B   = (unsigned short*)d_ws;          // N*256 bf16 (xt)
    unsigned short* Whi = B + (size_t)N * 256;            // 65536 ushort
    float* uspG  = (float*)(Whi + 65536);                 // 256 f
    float* u2G   = uspG + 256;                            // 8 f (4 used, pad to 16B)
    int* counts  = (int*)(u2G + 8);                       // N   (16B-aligned)
    int* cursor  = counts + N;                            // N
    int* starts  = cursor + N;                            // N+2
    int2* ep     = (int2*)(starts + N + 2);               // E

    // prep grid: 32 W-pack + 1 bias + 59 zeroing (15000 int4 = counts+cursor)
    prep_kernel<<<92, 256, 0, stream>>>(weight, Whi, bias, uspG, u2G, (int4*)counts);
    fused_front_hist_kernel<<<N / GR, 256, 0, stream>>>(x, Whi, uspG, u2G, B,
                                                        adj_row, counts);
    scan_kernel<<<1, 1024, 0, stream>>>(counts, starts, N);
    scatter_kernel<<<(E + 255) / 256, 256, 0, stream>>>(adj_row, adj_col, adj_val,
                                                        starts, cursor, ep, E);
    spmm_final_kernel<<<N / 4, 256, 0, stream>>>(B, ep, starts, (float4*)d_out);
}